// Round 1
// baseline (1465.091 us; speedup 1.0000x reference)
//
#include <hip/hip_runtime.h>

// MultiHeadAttention: B=4, S=4096, D=2048, H=16, HD=128 (per-token attention,
// no sequence mixing). 4 big GEMMs (bf16 MFMA, f32 accum) + tiny f32 softmax-mix.
//
// Pipeline (all on `stream`, scratch in d_ws, Q parked in d_out):
//   cvt W{q,k,v,o} -> bf16            (ws)
//   cvt q -> xb ; GEMM -> Q f32       (d_out)
//   cvt k -> xb ; GEMM -> K f32       (ws)
//   cvt v -> xb ; GEMM -> V bf16      (ws)
//   attn(Q,K,V) -> attn bf16          (ws, aliases xb)
//   GEMM attn x Wo^T + bo -> d_out f32

#define AS1 __attribute__((address_space(1)))
#define AS3 __attribute__((address_space(3)))

typedef __bf16 bf16x8 __attribute__((ext_vector_type(8)));
typedef float  f32x4  __attribute__((ext_vector_type(4)));
typedef unsigned short u16x8 __attribute__((ext_vector_type(8)));

static constexpr int MTOK = 16384;   // B*S
static constexpr int DIM  = 2048;    // D

__device__ __forceinline__ unsigned short f2bf(float x) {
  unsigned u = __float_as_uint(x);
  u += 0x7fffu + ((u >> 16) & 1u);   // round-to-nearest-even
  return (unsigned short)(u >> 16);
}
__device__ __forceinline__ float bf2f(unsigned short h) {
  return __uint_as_float(((unsigned)h) << 16);
}

// ---------------------------------------------------------------- cvt f32->bf16
__global__ __launch_bounds__(256)
void cvt_f32_bf16(const float* __restrict__ in, unsigned short* __restrict__ out,
                  size_t n8) {
  size_t i = (size_t)blockIdx.x * 256 + threadIdx.x;
  if (i >= n8) return;
  const f32x4* p = (const f32x4*)in + i * 2;
  f32x4 a = p[0];
  f32x4 b = p[1];
  u16x8 r;
  r[0] = f2bf(a[0]); r[1] = f2bf(a[1]); r[2] = f2bf(a[2]); r[3] = f2bf(a[3]);
  r[4] = f2bf(b[0]); r[5] = f2bf(b[1]); r[6] = f2bf(b[2]); r[7] = f2bf(b[3]);
  ((u16x8*)out)[i] = r;
}

// ------------------------------------------------- GEMM C = A * B^T + bias
// A[M][K] bf16 row-major, B[N][K] bf16 row-major (i.e. B^T layout), C f32 or bf16.
// 128x128 tile, BK=64, 256 threads (4 waves, 2x2), mfma_f32_16x16x32_bf16,
// global_load_lds width-16 staging, 2-barrier K-loop (m97 structure).
template <int BF16OUT>
__global__ __launch_bounds__(256)
void gemm_bt(const unsigned short* __restrict__ A,
             const unsigned short* __restrict__ Bm,
             const float* __restrict__ bias,
             void* __restrict__ C,
             const int M, const int N, const int K) {
  __shared__ unsigned short Alds[128 * 64];
  __shared__ unsigned short Blds[128 * 64];

  const int tid = threadIdx.x;
  const int w   = tid >> 6;
  const int l   = tid & 63;
  const int bm  = blockIdx.y << 7;
  const int bn  = blockIdx.x << 7;

  // staging: per global_load_lds, each wave writes 1KB = 8 rows of 64 bf16.
  // lane l -> row +l/8, col (l&7)*8 ; inst j covers rows j*32 + w*8 .. +8
  const int srow = (w << 3) + (l >> 3);
  const int scol = (l & 7) << 3;
  const unsigned short* Ag = A  + (size_t)(bm + srow) * K + scol;
  const unsigned short* Bg = Bm + (size_t)(bn + srow) * K + scol;

  const int wr    = (w >> 1) << 6;   // wave row base in tile
  const int wc    = (w & 1) << 6;    // wave col base in tile
  const int lrow  = l & 15;
  const int lhalf = l >> 4;

  f32x4 acc[4][4];
#pragma unroll
  for (int mi = 0; mi < 4; ++mi)
#pragma unroll
    for (int ni = 0; ni < 4; ++ni)
      acc[mi][ni] = (f32x4){0.f, 0.f, 0.f, 0.f};

  for (int k0 = 0; k0 < K; k0 += 64) {
#pragma unroll
    for (int j = 0; j < 4; ++j) {
      __builtin_amdgcn_global_load_lds(
          (const AS1 void*)(Ag + (size_t)(j * 32) * K + k0),
          (AS3 void*)(&Alds[(j * 32 + w * 8) * 64]), 16, 0, 0);
      __builtin_amdgcn_global_load_lds(
          (const AS1 void*)(Bg + (size_t)(j * 32) * K + k0),
          (AS3 void*)(&Blds[(j * 32 + w * 8) * 64]), 16, 0, 0);
    }
    __syncthreads();   // drains vmcnt before LDS reads

#pragma unroll
    for (int kk = 0; kk < 64; kk += 32) {
      bf16x8 af[4], bfr[4];
#pragma unroll
      for (int mi = 0; mi < 4; ++mi)
        af[mi] = *(const bf16x8*)&Alds[(wr + mi * 16 + lrow) * 64 + kk + lhalf * 8];
#pragma unroll
      for (int ni = 0; ni < 4; ++ni)
        bfr[ni] = *(const bf16x8*)&Blds[(wc + ni * 16 + lrow) * 64 + kk + lhalf * 8];
#pragma unroll
      for (int mi = 0; mi < 4; ++mi)
#pragma unroll
        for (int ni = 0; ni < 4; ++ni)
          acc[mi][ni] = __builtin_amdgcn_mfma_f32_16x16x32_bf16(
              af[mi], bfr[ni], acc[mi][ni], 0, 0, 0);
    }
    __syncthreads();   // protect LDS before next stage
  }

  // epilogue: C/D layout col = lane&15, row = (lane>>4)*4 + r  [m89-verified]
#pragma unroll
  for (int ni = 0; ni < 4; ++ni) {
    const int col = bn + wc + ni * 16 + lrow;
    const float bias_v = bias[col];
#pragma unroll
    for (int mi = 0; mi < 4; ++mi) {
      const int row0 = bm + wr + mi * 16 + lhalf * 4;
#pragma unroll
      for (int r = 0; r < 4; ++r) {
        const float val = acc[mi][ni][r] + bias_v;
        if (BF16OUT)
          ((unsigned short*)C)[(size_t)(row0 + r) * N + col] = f2bf(val);
        else
          ((float*)C)[(size_t)(row0 + r) * N + col] = val;
      }
    }
  }
}

// ------------------------------------------------------- per-token attention
// One wave per token. Lane l holds 32 contiguous channels (head h = l>>2,
// quarter qtr = l&3). score[h][g] via shuffled K, lane-local softmax over g,
// PV via shuffled V. Writes attn as bf16.
__global__ __launch_bounds__(256)
void attn_tok(const float* __restrict__ Qf, const float* __restrict__ Kf,
              const unsigned short* __restrict__ Vb,
              unsigned short* __restrict__ Ob) {
  const int w = threadIdx.x >> 6;
  const int l = threadIdx.x & 63;
  const size_t t    = (size_t)blockIdx.x * 4 + w;
  const size_t base = t * DIM + (size_t)l * 32;
  const int qtr = l & 3;

  float q[32], kr[32];
  {
    const f32x4* qp = (const f32x4*)(Qf + base);
    const f32x4* kp = (const f32x4*)(Kf + base);
#pragma unroll
    for (int j = 0; j < 8; ++j) {
      f32x4 a = qp[j];
      f32x4 b = kp[j];
      q[4 * j + 0] = a[0]; q[4 * j + 1] = a[1]; q[4 * j + 2] = a[2]; q[4 * j + 3] = a[3];
      kr[4 * j + 0] = b[0]; kr[4 * j + 1] = b[1]; kr[4 * j + 2] = b[2]; kr[4 * j + 3] = b[3];
    }
  }

  // score[h][g] = sum_d Q[h][d]*K[g][d]; each lane accumulates its d-quarter,
  // then sums across the 4 quarter-lanes of head h.
  float s[16];
#pragma unroll
  for (int g = 0; g < 16; ++g) {
    const int src = g * 4 + qtr;
    float p = 0.f;
#pragma unroll
    for (int j = 0; j < 32; ++j) p = fmaf(q[j], __shfl(kr[j], src, 64), p);
    p += __shfl_xor(p, 1, 64);
    p += __shfl_xor(p, 2, 64);
    s[g] = p;
  }

  // softmax over g (all data lane-local; 4 lanes/head redundantly compute it)
  float mx = s[0];
#pragma unroll
  for (int g = 1; g < 16; ++g) mx = fmaxf(mx, s[g]);
  float sum = 0.f;
#pragma unroll
  for (int g = 0; g < 16; ++g) { s[g] = __expf(s[g] - mx); sum += s[g]; }
  const float inv = 1.0f / sum;

  float vr[32];
  {
    const u16x8* vp = (const u16x8*)(Vb + base);
#pragma unroll
    for (int j = 0; j < 4; ++j) {
      u16x8 h8 = vp[j];
#pragma unroll
      for (int c = 0; c < 8; ++c) vr[8 * j + c] = bf2f(h8[c]);
    }
  }

  float o[32];
#pragma unroll
  for (int j = 0; j < 32; ++j) o[j] = 0.f;
#pragma unroll
  for (int g = 0; g < 16; ++g) {
    const float wg = s[g] * inv;
    const int src = g * 4 + qtr;
#pragma unroll
    for (int j = 0; j < 32; ++j) o[j] = fmaf(wg, __shfl(vr[j], src, 64), o[j]);
  }

  unsigned short* op = Ob + base;
#pragma unroll
  for (int j = 0; j < 4; ++j) {
    u16x8 r;
#pragma unroll
    for (int c = 0; c < 8; ++c) r[c] = f2bf(o[8 * j + c]);
    *(u16x8*)(op + 8 * j) = r;
  }
}

// ---------------------------------------------------------------- launch
extern "C" void kernel_launch(void* const* d_in, const int* in_sizes, int n_in,
                              void* d_out, int out_size, void* d_ws, size_t ws_size,
                              hipStream_t stream) {
  (void)in_sizes; (void)n_in; (void)out_size;

  const float* q  = (const float*)d_in[0];
  const float* k  = (const float*)d_in[1];
  const float* v  = (const float*)d_in[2];
  const float* Wq = (const float*)d_in[3];
  const float* bq = (const float*)d_in[4];
  const float* Wk = (const float*)d_in[5];
  const float* bk = (const float*)d_in[6];
  const float* Wv = (const float*)d_in[7];
  const float* bv = (const float*)d_in[8];
  const float* Wo = (const float*)d_in[9];
  const float* bo = (const float*)d_in[10];

  // workspace layout (288 MiB total)
  const size_t XB_SZ = (size_t)MTOK * DIM * 2;   //  64 MiB bf16 input staging
  const size_t W_SZ  = (size_t)DIM * DIM * 2;    //   8 MiB per weight
  const size_t K_SZ  = (size_t)MTOK * DIM * 4;   // 128 MiB f32
  const size_t NEED  = XB_SZ + 4 * W_SZ + K_SZ + XB_SZ;
  if (ws_size < NEED) return;   // scratch too small: fail cleanly, not a fault

  char* ws = (char*)d_ws;
  unsigned short* xb    = (unsigned short*)(ws);
  unsigned short* Wqb   = (unsigned short*)(ws + XB_SZ);
  unsigned short* Wkb   = (unsigned short*)(ws + XB_SZ + 1 * W_SZ);
  unsigned short* Wvb   = (unsigned short*)(ws + XB_SZ + 2 * W_SZ);
  unsigned short* Wob   = (unsigned short*)(ws + XB_SZ + 3 * W_SZ);
  float*          Kf    = (float*)(ws + XB_SZ + 4 * W_SZ);
  unsigned short* Vbf   = (unsigned short*)(ws + XB_SZ + 4 * W_SZ + K_SZ);
  unsigned short* attnb = xb;            // xb dead once V-GEMM has run
  float*          Qf    = (float*)d_out; // Q parked in d_out; dead before final GEMM

  const size_t nW8 = (size_t)DIM * DIM / 8;     // 524288  -> 2048 blocks
  const size_t nX8 = (size_t)MTOK * DIM / 8;    // 4194304 -> 16384 blocks
  const dim3 ggrid(DIM / 128, MTOK / 128);      // 16 x 128

  // weights -> bf16
  cvt_f32_bf16<<<2048, 256, 0, stream>>>(Wq, Wqb, nW8);
  cvt_f32_bf16<<<2048, 256, 0, stream>>>(Wk, Wkb, nW8);
  cvt_f32_bf16<<<2048, 256, 0, stream>>>(Wv, Wvb, nW8);
  cvt_f32_bf16<<<2048, 256, 0, stream>>>(Wo, Wob, nW8);

  // Q = q @ Wq^T + bq   (f32, into d_out)
  cvt_f32_bf16<<<16384, 256, 0, stream>>>(q, xb, nX8);
  gemm_bt<0><<<ggrid, 256, 0, stream>>>(xb, Wqb, bq, (void*)Qf, MTOK, DIM, DIM);
  // K = k @ Wk^T + bk   (f32)
  cvt_f32_bf16<<<16384, 256, 0, stream>>>(k, xb, nX8);
  gemm_bt<0><<<ggrid, 256, 0, stream>>>(xb, Wkb, bk, (void*)Kf, MTOK, DIM, DIM);
  // V = v @ Wv^T + bv   (bf16)
  cvt_f32_bf16<<<16384, 256, 0, stream>>>(v, xb, nX8);
  gemm_bt<1><<<ggrid, 256, 0, stream>>>(xb, Wvb, bv, (void*)Vbf, MTOK, DIM, DIM);

  // per-token attention -> attn bf16 (aliases xb)
  attn_tok<<<MTOK / 4, 256, 0, stream>>>(Qf, Kf, Vbf, attnb);

  // out = attn @ Wo^T + bo  (f32, d_out)
  gemm_bt<0><<<ggrid, 256, 0, stream>>>(attnb, Wob, bo, d_out, MTOK, DIM, DIM);
}